// Round 10
// baseline (268.615 us; speedup 1.0000x reference)
//
#include <hip/hip_runtime.h>
#include <math.h>

#define NROWS 65536
#define DDIM 2048
#define NEXP 64
#define TOPK 8

constexpr int BM = 128;          // rows per block (4 waves x 32 rows)
constexpr int NTH = 256;
constexpr int NSTEP = 64;        // k-steps of 32
constexpr int CAP = 1024;        // overflow flagged-row capacity (expect 0)
constexpr int FCAP = 16;         // per-wave inline flag capacity (mean ~1.1, P(>16)~0)
constexpr float THR = 3e-4f;     // ambiguity gap threshold (split-bf16 err rms ~4e-6)
constexpr int WFRAG_STEP = 4096; // shorts per k-step: [hl 2][ct 4][lane 64][j 8]

typedef short bf16x8 __attribute__((ext_vector_type(8)));
typedef float f32x4 __attribute__((ext_vector_type(4)));

__device__ inline unsigned short bfround(float f) {
    union { float f; unsigned u; } v; v.f = f;
    unsigned r = (v.u + 0x7fffu + ((v.u >> 16) & 1u)) >> 16;   // RNE
    return (unsigned short)r;
}
__device__ inline float bf2f(unsigned short h) {
    union { unsigned u; float f; } v; v.u = ((unsigned)h) << 16;
    return v.f;
}
__device__ inline void cvt8(const float4& A, const float4& B, bf16x8& h, bf16x8& l) {
    float f[8] = {A.x, A.y, A.z, A.w, B.x, B.y, B.z, B.w};
#pragma unroll
    for (int j = 0; j < 8; ++j) {
        unsigned short hh = bfround(f[j]);
        h[j] = (short)hh;
        l[j] = (short)bfround(f[j] - bf2f(hh));
    }
}

// One-shot: W fp32 [64][2048] -> bf16 hi/lo in MFMA B-fragment order.
// wfrag[t][hl][ct][lane][j]; expert e=ct*16+(lane&15), k=t*32+(lane>>4)*8+j.
__global__ __launch_bounds__(256)
void prep_kernel(const float* __restrict__ W, short* __restrict__ wfrag)
{
    const int t = blockIdx.x;           // 0..63
    const int tid = threadIdx.x;
    const int ct = tid >> 6, lane = tid & 63;
    const int e = ct * 16 + (lane & 15);
    const int k = t * 32 + (lane >> 4) * 8;
    const float* wp = W + (size_t)e * DDIM + k;
    float4 a = *reinterpret_cast<const float4*>(wp);
    float4 b = *reinterpret_cast<const float4*>(wp + 4);
    bf16x8 h, l;
    cvt8(a, b, h, l);
    short* base = wfrag + (size_t)t * WFRAG_STEP;
    *reinterpret_cast<bf16x8*>(base + (ct * 64 + lane) * 8) = h;          // hl=0
    *reinterpret_cast<bf16x8*>(base + 2048 + (ct * 64 + lane) * 8) = l;   // hl=1
}

// ws layout (words): [0..63] psum | [64..127] freq | [128] zsum | [129] cnt
//   [130..130+CAP) overflow rows | [130+CAP..) overflow logits (64/row)
//   [WFRAG_OFF..) W bf16 fragments (512 KB)
// Barrier-free K-loop: B from global fragments (coalesced, L2-hot), A register-
// double-buffered from this lane's own rows. fp64 recheck is INLINE per wave.
__global__ __launch_bounds__(NTH, 1)
void gate_kernel(const float* __restrict__ x, const short* __restrict__ wfrag,
                 const float* __restrict__ W,
                 float* __restrict__ out_idx, float* __restrict__ out_gate,
                 float* __restrict__ g_psum, float* __restrict__ g_freq,
                 float* __restrict__ g_zsum, int* __restrict__ g_cnt,
                 int* __restrict__ g_rows, float* __restrict__ g_logits)
{
    __shared__ float psum_s[NEXP];
    __shared__ float fcnt_s[NEXP];
    __shared__ float fRow[4][FCAP][NEXP];   // per-wave flagged-row logits
    __shared__ int fId[4][FCAP];
    __shared__ int fN[4];

    const int tid = threadIdx.x;
    const int w = tid >> 6;          // wave 0..3
    const int lane = tid & 63;
    const int g = lane >> 4;         // k-subgroup (A) / row subgroup (C)
    const int c = lane & 15;         // A row offset / C col offset
    const int row0 = blockIdx.x * BM + w * 32;

    if (tid < NEXP) { psum_s[tid] = 0.f; fcnt_s[tid] = 0.f; }
    if (lane == 0) fN[w] = 0;
    __syncthreads();                 // init visible before any epilogue atomics

    // A source pointers (lane's rows), offset by k-subgroup
    const float* xr0 = x + (size_t)(row0 + c) * DDIM + g * 8;
    const float* xr1 = x + (size_t)(row0 + 16 + c) * DDIM + g * 8;

    f32x4 acc[2][4];
#pragma unroll
    for (int rt = 0; rt < 2; ++rt)
#pragma unroll
        for (int ct = 0; ct < 4; ++ct) acc[rt][ct] = (f32x4){0.f, 0.f, 0.f, 0.f};

    float4 xa[2][2], xb[2][2];
    xa[0][0] = *reinterpret_cast<const float4*>(xr0);
    xa[0][1] = *reinterpret_cast<const float4*>(xr0 + 4);
    xa[1][0] = *reinterpret_cast<const float4*>(xr1);
    xa[1][1] = *reinterpret_cast<const float4*>(xr1 + 4);

    for (int t = 0; t < NSTEP; ++t) {
        // B fragments direct from global (lane-linear 16B -> 1KB/wave coalesced)
        const short* wt = wfrag + (size_t)t * WFRAG_STEP;
        bf16x8 bh[4], bl[4];
#pragma unroll
        for (int ct = 0; ct < 4; ++ct) {
            bh[ct] = *reinterpret_cast<const bf16x8*>(wt + (ct * 64 + lane) * 8);
            bl[ct] = *reinterpret_cast<const bf16x8*>(wt + 2048 + (ct * 64 + lane) * 8);
        }
        // A prefetch next step
        const int kn = (t + 1) * 32;
        if (t + 1 < NSTEP) {
            xb[0][0] = *reinterpret_cast<const float4*>(xr0 + kn);
            xb[0][1] = *reinterpret_cast<const float4*>(xr0 + kn + 4);
            xb[1][0] = *reinterpret_cast<const float4*>(xr1 + kn);
            xb[1][1] = *reinterpret_cast<const float4*>(xr1 + kn + 4);
        }
        bf16x8 ah[2], al[2];
        cvt8(xa[0][0], xa[0][1], ah[0], al[0]);
        cvt8(xa[1][0], xa[1][1], ah[1], al[1]);
        // 3-term split-bf16: x*w = xh*wh + xh*wl + xl*wh (xl*wl ~4e-6, dropped)
#pragma unroll
        for (int rt = 0; rt < 2; ++rt)
#pragma unroll
            for (int ct = 0; ct < 4; ++ct) {
                acc[rt][ct] = __builtin_amdgcn_mfma_f32_16x16x32_bf16(
                    ah[rt], bh[ct], acc[rt][ct], 0, 0, 0);
                acc[rt][ct] = __builtin_amdgcn_mfma_f32_16x16x32_bf16(
                    ah[rt], bl[ct], acc[rt][ct], 0, 0, 0);
                acc[rt][ct] = __builtin_amdgcn_mfma_f32_16x16x32_bf16(
                    al[rt], bh[ct], acc[rt][ct], 0, 0, 0);
            }
#pragma unroll
        for (int rt = 0; rt < 2; ++rt)
#pragma unroll
            for (int i = 0; i < 2; ++i) xa[rt][i] = xb[rt][i];
    }

    // ---- epilogue ----
    // C/D layout (m89): acc[rt][ct][reg] = C[row0 + rt*16 + g*4 + reg][ct*16 + c].
    float pcol[4] = {0.f, 0.f, 0.f, 0.f};
    float zsq_acc = 0.f;

#pragma unroll
    for (int rt = 0; rt < 2; ++rt) {
#pragma unroll
        for (int reg = 0; reg < 4; ++reg) {
            const int row = row0 + rt * 16 + g * 4 + reg;
            float ld[4];
#pragma unroll
            for (int ct = 0; ct < 4; ++ct) ld[ct] = acc[rt][ct][reg];

            float tv[9]; int ti[9];
#pragma unroll
            for (int p = 0; p < 9; ++p) {   // top-8 + rank-9 (gap test)
                float bv = -3.4e38f; int bgi = 127;
#pragma unroll
                for (int ct = 0; ct < 4; ++ct) {
                    int e = ct * 16 + c;
                    if (ld[ct] > bv) { bv = ld[ct]; bgi = e; }
                }
#pragma unroll
                for (int m = 1; m < 16; m <<= 1) {   // width-16: stays in g-group
                    float ov = __shfl_xor(bv, m, 16);
                    int ogi = __shfl_xor(bgi, m, 16);
                    if (ov > bv || (ov == bv && ogi < bgi)) { bv = ov; bgi = ogi; }
                }
                tv[p] = bv; ti[p] = bgi;
#pragma unroll
                for (int ct = 0; ct < 4; ++ct)
                    if (bgi == ct * 16 + c) ld[ct] = -3.4e38f;
            }

            float mg = 3.4e38f;
#pragma unroll
            for (int p = 0; p < 8; ++p) mg = fminf(mg, tv[p] - tv[p + 1]);
            const bool flagged = (mg < THR);   // uniform across the 16-lane group
            if (flagged) {
                int slot = 0;
                if (c == 0) slot = atomicAdd(&fN[w], 1);
                slot = __shfl(slot, (lane >> 4) << 4, 64);
                if (slot < FCAP) {             // inline list (normal path)
                    if (c == 0) fId[w][slot] = row;
#pragma unroll
                    for (int ct = 0; ct < 4; ++ct)
                        fRow[w][slot][ct * 16 + c] = acc[rt][ct][reg];
                } else {                       // overflow -> global fixup net
                    int idx = 0;
                    if (c == 0) idx = atomicAdd(g_cnt, 1);
                    idx = __shfl(idx, (lane >> 4) << 4, 64);
                    if (idx < CAP) {
                        if (c == 0) g_rows[idx] = row;
#pragma unroll
                        for (int ct = 0; ct < 4; ++ct)
                            g_logits[(size_t)idx * NEXP + ct * 16 + c] = acc[rt][ct][reg];
                    }
                }
            }

            // full softmax probs (psum)
            const float m0 = tv[0];
            float pe[4], ps = 0.f;
#pragma unroll
            for (int ct = 0; ct < 4; ++ct) {
                pe[ct] = expf(acc[rt][ct][reg] - m0);
                ps += pe[ct];
            }
            float s = ps;
#pragma unroll
            for (int m = 1; m < 16; m <<= 1) s += __shfl_xor(s, m, 16);
            const float inv_s = 1.f / s;
#pragma unroll
            for (int ct = 0; ct < 4; ++ct) pcol[ct] += pe[ct] * inv_s;

            if (c == 0) {   // z-loss: logaddexp(lse, log(1e-5))^2
                float lsef = m0 + logf(s);
                const float lb = -11.512925464970229f;
                float mx = fmaxf(lsef, lb), mn = fminf(lsef, lb);
                float z = mx + log1pf(expf(mn - mx));
                zsq_acc += z * z;
            }

            // top-k gates (flagged rows: freq counting deferred to recheck)
            float gs = 0.f;
#pragma unroll
            for (int p = 0; p < 8; ++p) gs += expf(tv[p] - m0);
            if (c < 8) {
                float mytv = tv[0]; int myti = ti[0];
#pragma unroll
                for (int p = 1; p < 8; ++p)
                    if (c == p) { mytv = tv[p]; myti = ti[p]; }
                const size_t base = (size_t)row * TOPK;
                out_idx[base + c] = (float)myti;
                out_gate[base + c] = expf(mytv - m0) / gs;
                if (!flagged) atomicAdd(&fcnt_s[myti], 1.f);
            }
        }
    }

    // ---- inline fp64 recheck of this wave's flagged rows ----
    const int nf = min(fN[w], FCAP);
    for (int s = 0; s < nf; ++s) {
        const int R = fId[w][s];
        const float myLog = fRow[w][s][lane];   // lane == expert
        // 9th-largest fp32 logit (idx tie-break) -> candidate cutoff
        float vv = myLog, v9 = 0.f;
#pragma unroll
        for (int p = 0; p < 9; ++p) {
            float bv = vv; int bgi = lane;
#pragma unroll
            for (int m = 1; m < 64; m <<= 1) {
                float ov = __shfl_xor(bv, m, 64);
                int ogi = __shfl_xor(bgi, m, 64);
                if (ov > bv || (ov == bv && ogi < bgi)) { bv = ov; bgi = ogi; }
            }
            v9 = bv;
            if (lane == bgi) vv = -3.4e38f;
        }
        const bool cand = (myLog >= v9 - THR);
        unsigned long long cm = __ballot(cand);

        // x row -> registers once (coalesced 1KB/instr)
        const float* xrw = x + (size_t)R * DDIM;
        float4 xv[8];
#pragma unroll
        for (int j = 0; j < 8; ++j)
            xv[j] = *reinterpret_cast<const float4*>(xrw + j * 256 + lane * 4);

        // serial coalesced fp64 dots over candidates (cm wave-uniform)
        double myD = -HUGE_VAL;
        unsigned long long m2 = cm;
        while (m2) {
            const int e = (int)__ffsll((unsigned long long)m2) - 1;
            m2 &= (m2 - 1);
            const float* wrp = W + (size_t)e * DDIM;
            double p0 = 0.0, p1 = 0.0, p2 = 0.0, p3 = 0.0;
#pragma unroll
            for (int j = 0; j < 8; ++j) {
                float4 wv = *reinterpret_cast<const float4*>(wrp + j * 256 + lane * 4);
                p0 = fma((double)xv[j].x, (double)wv.x, p0);
                p1 = fma((double)xv[j].y, (double)wv.y, p1);
                p2 = fma((double)xv[j].z, (double)wv.z, p2);
                p3 = fma((double)xv[j].w, (double)wv.w, p3);
            }
            double sd = (p0 + p1) + (p2 + p3);
#pragma unroll
            for (int m = 1; m < 64; m <<= 1) sd += __shfl_xor(sd, m, 64);
            if (lane == e) myD = sd;   // all lanes hold sd; owner keeps it
        }

        // exact top-8 among candidates (fp64, expert-id tie-break)
        double v = cand ? myD : -HUGE_VAL;
        double tvd[8]; int tid8[8];
#pragma unroll
        for (int p = 0; p < 8; ++p) {
            double bv = v; int bgi = lane;
#pragma unroll
            for (int m = 1; m < 64; m <<= 1) {
                double ov = __shfl_xor(bv, m, 64);
                int ogi = __shfl_xor(bgi, m, 64);
                if (ov > bv || (ov == bv && ogi < bgi)) { bv = ov; bgi = ogi; }
            }
            tvd[p] = bv; tid8[p] = bgi;
            if (lane == bgi) v = -HUGE_VAL;
        }
        const double m0 = tvd[0];
        double gsum = 0.0, ge[8];
#pragma unroll
        for (int j = 0; j < 8; ++j) { ge[j] = exp(tvd[j] - m0); gsum += ge[j]; }
        if (lane < 8) {
            double myge = ge[0]; int myti = tid8[0];
#pragma unroll
            for (int j = 1; j < 8; ++j)
                if (lane == j) { myge = ge[j]; myti = tid8[j]; }
            const size_t base = (size_t)R * TOPK;
            out_idx[base + lane] = (float)myti;
            out_gate[base + lane] = (float)(myge / gsum);
            atomicAdd(&fcnt_s[myti], 1.f);     // final (exact) freq counts
        }
    }

    // z-loss wave reduction -> global
#pragma unroll
    for (int off = 32; off > 0; off >>= 1) zsq_acc += __shfl_down(zsq_acc, off, 64);
    if (lane == 0) atomicAdd(g_zsum, zsq_acc);

    // probs column sums -> shared -> global
#pragma unroll
    for (int ct = 0; ct < 4; ++ct) atomicAdd(&psum_s[ct * 16 + c], pcol[ct]);
    __syncthreads();
    if (tid < NEXP) {
        atomicAdd(&g_psum[tid], psum_s[tid]);
        atomicAdd(&g_freq[tid], fcnt_s[tid]);
    }
}

// Overflow net only (expected n == 0): fp64 recheck via candidate pruning.
__global__ __launch_bounds__(256, 1)
void fixup_kernel(const float* __restrict__ x, const float* __restrict__ W,
                  float* __restrict__ out_idx, float* __restrict__ out_gate,
                  float* __restrict__ g_freq,
                  const int* __restrict__ g_cnt, const int* __restrict__ g_rows,
                  const float* __restrict__ g_logits)
{
    const int n = min(*g_cnt, CAP);
    const int tid = threadIdx.x;
    const int grp = tid >> 5;
    const int gl = tid & 31;
    __shared__ float sLog[NEXP];
    __shared__ double sD[16];
    __shared__ int sCand[16];
    __shared__ int sNc;

    for (int i = blockIdx.x; i < n; i += gridDim.x) {
        const int row = g_rows[i];
        if (tid < NEXP) sLog[tid] = g_logits[(size_t)i * NEXP + tid];
        if (tid == 0) sNc = 0;
        __syncthreads();

        if (tid < NEXP) {
            const int lane = tid;
            const float myv = sLog[lane];
            float vv = myv, v9 = 0.f;
#pragma unroll
            for (int p = 0; p < 9; ++p) {
                float bv = vv; int bgi = lane;
#pragma unroll
                for (int m = 1; m < 64; m <<= 1) {
                    float ov = __shfl_xor(bv, m, 64);
                    int ogi = __shfl_xor(bgi, m, 64);
                    if (ov > bv || (ov == bv && ogi < bgi)) { bv = ov; bgi = ogi; }
                }
                if (lane == bgi) vv = -3.4e38f;
                v9 = bv;
            }
            if (myv >= v9 - THR) {
                int slot = atomicAdd(&sNc, 1);
                if (slot < 16) sCand[slot] = lane;
            }
        }
        __syncthreads();
        const int nc = min(sNc, 16);

        const float* xr = x + (size_t)row * DDIM;
        for (int cb = 0; cb < nc; cb += 8) {
            const int ci = cb + grp;
            if (ci < nc) {
                const float* wr = W + (size_t)sCand[ci] * DDIM;
                double p0 = 0.0, p1 = 0.0, p2 = 0.0, p3 = 0.0;
#pragma unroll
                for (int j = 0; j < 16; ++j) {
                    const int k = j * 128 + gl * 4;
                    float4 wv = *reinterpret_cast<const float4*>(wr + k);
                    float4 xvv = *reinterpret_cast<const float4*>(xr + k);
                    p0 = fma((double)xvv.x, (double)wv.x, p0);
                    p1 = fma((double)xvv.y, (double)wv.y, p1);
                    p2 = fma((double)xvv.z, (double)wv.z, p2);
                    p3 = fma((double)xvv.w, (double)wv.w, p3);
                }
                double sd = (p0 + p1) + (p2 + p3);
#pragma unroll
                for (int m = 1; m < 32; m <<= 1) sd += __shfl_xor(sd, m, 32);
                if (gl == 0) sD[ci] = sd;
            }
        }
        __syncthreads();

        if (tid < NEXP) {
            const int lane = tid;
            double v = (lane < nc) ? sD[lane] : -HUGE_VAL;
            int id = (lane < nc) ? sCand[lane] : 1000;
            double tv[8]; int ti[8];
#pragma unroll
            for (int p = 0; p < 8; ++p) {
                double bv = v; int bgi = id;
#pragma unroll
                for (int m = 1; m < 64; m <<= 1) {
                    double ov = __shfl_xor(bv, m, 64);
                    int ogi = __shfl_xor(bgi, m, 64);
                    if (ov > bv || (ov == bv && ogi < bgi)) { bv = ov; bgi = ogi; }
                }
                tv[p] = bv; ti[p] = bgi;
                if (id == bgi) v = -HUGE_VAL;
            }
            const double m0 = tv[0];
            double gs = 0.0, ge[8];
#pragma unroll
            for (int j = 0; j < 8; ++j) { ge[j] = exp(tv[j] - m0); gs += ge[j]; }
            if (lane < 8) {
                double myge = ge[0]; int myti = ti[0];
#pragma unroll
                for (int j = 1; j < 8; ++j)
                    if (lane == j) { myge = ge[j]; myti = ti[j]; }
                const size_t base = (size_t)row * TOPK;
                out_idx[base + lane] = (float)myti;
                out_gate[base + lane] = (float)(myge / gs);
                atomicAdd(&g_freq[myti], 1.0f);   // deferred freq for overflow rows
            }
        }
        __syncthreads();
    }
}

__global__ void finalize_kernel(const float* __restrict__ g_psum,
                                const float* __restrict__ g_freq,
                                const float* __restrict__ g_zsum,
                                float* __restrict__ out_loss)
{
    const int lane = threadIdx.x & 63;
    float p = g_psum[lane], f = g_freq[lane];
    float sp = p, sf = f;
#pragma unroll
    for (int m = 1; m < 64; m <<= 1) { sp += __shfl_xor(sp, m, 64); sf += __shfl_xor(sf, m, 64); }
    sp = fmaxf(sp, 1e-12f);
    sf = fmaxf(sf, 1e-12f);
    float term = (p / sp) * (f / sf);
#pragma unroll
    for (int m = 1; m < 64; m <<= 1) term += __shfl_xor(term, m, 64);
    if (lane == 0)
        out_loss[0] = (float)NEXP * term + 0.1f * (g_zsum[0] / (float)NROWS);
}

extern "C" void kernel_launch(void* const* d_in, const int* in_sizes, int n_in,
                              void* d_out, int out_size, void* d_ws, size_t ws_size,
                              hipStream_t stream)
{
    const float* x = (const float*)d_in[0];
    const float* W = (const float*)d_in[1];
    float* out = (float*)d_out;
    float* out_idx  = out;
    float* out_gate = out + (size_t)NROWS * TOPK;
    float* out_loss = out + (size_t)2 * NROWS * TOPK;

    float* acc    = (float*)d_ws;               // psum[64] | freq[64] | zsum | cnt
    int*   cnt    = (int*)d_ws + 129;
    int*   rows   = (int*)d_ws + 130;
    float* logits = (float*)d_ws + 130 + CAP;   // CAP x 64 overflow logits
    // 16B-aligned W-fragment buffer after the above (130+1024+65536 = 66690 -> 66704)
    short* wfrag  = (short*)((float*)d_ws + 66704);
    hipMemsetAsync(d_ws, 0, 130 * sizeof(float), stream);

    prep_kernel<<<NSTEP, 256, 0, stream>>>(W, wfrag);
    gate_kernel<<<NROWS / BM, NTH, 0, stream>>>(
        x, wfrag, W, out_idx, out_gate, acc, acc + NEXP, acc + 2 * NEXP,
        cnt, rows, logits);
    fixup_kernel<<<64, 256, 0, stream>>>(x, W, out_idx, out_gate, acc + NEXP,
                                         cnt, rows, logits);
    finalize_kernel<<<1, 64, 0, stream>>>(acc, acc + NEXP, acc + 2 * NEXP, out_loss);
}